// Round 1
// baseline (797.861 us; speedup 1.0000x reference)
//
#include <hip/hip_runtime.h>
#include <stdint.h>

typedef unsigned short u16;
typedef __attribute__((ext_vector_type(8))) short short8;
typedef __attribute__((ext_vector_type(8))) u16 ushort8;
typedef __attribute__((ext_vector_type(4))) float f32x4;

#define B_ 32
#define T_ 1024
#define D_ 512
#define H_ 2048
#define E_ 8

__device__ __forceinline__ u16 f2bf(float f) {
  union { float f; uint32_t u; } v; v.f = f;
  uint32_t u = v.u;
  uint32_t r = (u + 0x7fffu + ((u >> 16) & 1u)) >> 16;
  return (u16)r;
}

__device__ __forceinline__ void gload16(const void* g, void* l) {
  __builtin_amdgcn_global_load_lds(
      (const __attribute__((address_space(1))) unsigned int*)g,
      (__attribute__((address_space(3))) unsigned int*)l, 16, 0, 0);
}

// ---------------- conversion / transpose ----------------

__global__ void k_convert_x(const float* __restrict__ in, u16* __restrict__ out, int n8) {
  int i = blockIdx.x * 256 + threadIdx.x;
  if (i >= n8) return;
  const float4* p = reinterpret_cast<const float4*>(in) + (size_t)i * 2;
  float4 a = p[0], b = p[1];
  ushort8 r;
  r[0] = f2bf(a.x); r[1] = f2bf(a.y); r[2] = f2bf(a.z); r[3] = f2bf(a.w);
  r[4] = f2bf(b.x); r[5] = f2bf(b.y); r[6] = f2bf(b.z); r[7] = f2bf(b.w);
  reinterpret_cast<ushort8*>(out)[i] = r;
}

// in: [E][R][C] f32  ->  out: [E][C][R] bf16
__global__ void k_transpose_bf16(const float* __restrict__ in, u16* __restrict__ out,
                                 int R, int C) {
  __shared__ float tile[64][65];
  int e = blockIdx.z;
  int c0 = blockIdx.x * 64, r0 = blockIdx.y * 64;
  const float* src = in + (size_t)e * R * C;
  u16* dst = out + (size_t)e * R * C;
  int t = threadIdx.x;
#pragma unroll
  for (int i = 0; i < 16; i++) {
    int idx = i * 256 + t;
    int r = idx >> 6, c = idx & 63;
    tile[r][c] = src[(size_t)(r0 + r) * C + (c0 + c)];
  }
  __syncthreads();
#pragma unroll
  for (int i = 0; i < 16; i++) {
    int idx = i * 256 + t;
    int c = idx >> 6, r = idx & 63;
    dst[(size_t)(c0 + c) * R + (r0 + r)] = f2bf(tile[r][c]);
  }
}

// ---------------- gating ----------------

// partial column sums over 16-row chunks: partial[b][c][d]
__global__ void k_pool_partial(const float* __restrict__ x, float* __restrict__ partial) {
  int b = blockIdx.y, c = blockIdx.x, t = threadIdx.x;
  const float* xp = x + ((size_t)b * T_ + c * 16) * D_;
  float s0 = 0.f, s1 = 0.f;
#pragma unroll
  for (int r = 0; r < 16; r++) {
    s0 += xp[r * D_ + t];
    s1 += xp[r * D_ + t + 256];
  }
  partial[((size_t)b * 64 + c) * D_ + t] = s0;
  partial[((size_t)b * 64 + c) * D_ + t + 256] = s1;
}

__global__ void k_gate(const float* __restrict__ partial, const float* __restrict__ gate_w,
                       const float* __restrict__ gate_b, float* __restrict__ gate_out,
                       int* __restrict__ eidx, float* __restrict__ ewt) {
  int b = blockIdx.x, t = threadIdx.x;
  __shared__ float pooled[D_];
  __shared__ float logits[E_];
  for (int d = t; d < D_; d += 256) {
    float s = 0.f;
    for (int c = 0; c < 64; c++) s += partial[((size_t)b * 64 + c) * D_ + d];
    pooled[d] = s * (1.0f / 1024.0f);
  }
  __syncthreads();
  if (t < E_) {
    float s = gate_b[t];
    for (int d = 0; d < D_; d++) s += pooled[d] * gate_w[d * E_ + t];
    logits[t] = s;
    gate_out[b * E_ + t] = s;
  }
  __syncthreads();
  if (t == 0) {
    int i1 = 0; float v1 = logits[0];
    for (int e = 1; e < E_; e++) if (logits[e] > v1) { v1 = logits[e]; i1 = e; }
    int i2 = -1; float v2 = -3.4e38f;
    for (int e = 0; e < E_; e++) {
      if (e == i1) continue;
      if (logits[e] > v2) { v2 = logits[e]; i2 = e; }
    }
    float e1 = __expf(v2 - v1);
    float den = 1.0f / (1.0f + e1);
    eidx[b * 2 + 0] = i1; eidx[b * 2 + 1] = i2;
    ewt[b * 2 + 0] = den; ewt[b * 2 + 1] = e1 * den;
  }
}

// ---------------- fused expert GEMMs ----------------
// A: [chunk][1024][K] bf16 row-major. W: [E][N][K] bf16 (N-major, i.e. pre-transposed).
// MODE 0: Hout[chunk][1024][N] = silu(A@W^T + b1[e])   (N=2048, K=512)
// MODE 1: Out[b]  = (k==0 ? X : Out) + wt*(A@W^T + b2[e])  (N=512, K=2048)
template <int N, int K, int MODE>
__global__ __launch_bounds__(256)
void moe_gemm(const u16* __restrict__ A, const u16* __restrict__ W,
              const float* __restrict__ bias, u16* __restrict__ Hout,
              float* __restrict__ Out, const float* __restrict__ Xres,
              const int* __restrict__ eidx, const float* __restrict__ ewt,
              int kpick, int bofs) {
  constexpr int NT = N / 128;
  const int ib = blockIdx.y;
  const int b = ib + bofs;
  const int tm = blockIdx.x / NT, tn = blockIdx.x % NT;
  const int e = eidx[b * 2 + kpick];
  const int tid = threadIdx.x;
  const int wave = tid >> 6, ln = tid & 63, hi = ln >> 4, l15 = ln & 15;
  const int wr = wave >> 1, wc = wave & 1;

  __shared__ u16 As[128 * 64];
  __shared__ u16 Bs[128 * 64];

  const u16* Ab = A + (size_t)ib * T_ * K + (size_t)(tm * 128) * K;
  const u16* Wb = W + (size_t)e * N * K + (size_t)(tn * 128) * K;

  f32x4 acc[4][4] = {};

  const int arow = tid >> 3;          // 0..31
  const int acol = (tid & 7) * 8;     // 0..56

  for (int kt = 0; kt < K / 64; kt++) {
    const int kb = kt * 64;
#pragma unroll
    for (int i = 0; i < 4; i++) {
      gload16(Ab + (size_t)(i * 32 + arow) * K + kb + acol, (u16*)As + i * 2048 + wave * 512);
      gload16(Wb + (size_t)(i * 32 + arow) * K + kb + acol, (u16*)Bs + i * 2048 + wave * 512);
    }
    __syncthreads();
#pragma unroll
    for (int kk = 0; kk < 2; kk++) {
      short8 af[4], bfr[4];
#pragma unroll
      for (int m = 0; m < 4; m++)
        af[m] = *reinterpret_cast<const short8*>(&As[(wr * 64 + m * 16 + l15) * 64 + kk * 32 + hi * 8]);
#pragma unroll
      for (int n = 0; n < 4; n++)
        bfr[n] = *reinterpret_cast<const short8*>(&Bs[(wc * 64 + n * 16 + l15) * 64 + kk * 32 + hi * 8]);
#pragma unroll
      for (int m = 0; m < 4; m++)
#pragma unroll
        for (int n = 0; n < 4; n++)
          acc[m][n] = __builtin_amdgcn_mfma_f32_16x16x32_bf16(af[m], bfr[n], acc[m][n], 0, 0, 0);
    }
    __syncthreads();
  }

  const float* be = bias + (size_t)e * N;
  if (MODE == 0) {
    u16* Hb = Hout + (size_t)ib * T_ * N;
#pragma unroll
    for (int m = 0; m < 4; m++) {
#pragma unroll
      for (int n = 0; n < 4; n++) {
        const int col = tn * 128 + wc * 64 + n * 16 + l15;
        const float bv = be[col];
#pragma unroll
        for (int j = 0; j < 4; j++) {
          const int row = tm * 128 + wr * 64 + m * 16 + hi * 4 + j;
          float z = acc[m][n][j] + bv;
          float hv = z / (1.0f + expf(-z));
          Hb[(size_t)row * N + col] = f2bf(hv);
        }
      }
    }
  } else {
    const float wt = ewt[b * 2 + kpick];
    float* Ob = Out + (size_t)b * T_ * D_;
    const float* Xb = Xres + (size_t)b * T_ * D_;
#pragma unroll
    for (int m = 0; m < 4; m++) {
#pragma unroll
      for (int n = 0; n < 4; n++) {
        const int col = tn * 128 + wc * 64 + n * 16 + l15;
        const float bv = be[col];
#pragma unroll
        for (int j = 0; j < 4; j++) {
          const int row = tm * 128 + wr * 64 + m * 16 + hi * 4 + j;
          float y = acc[m][n][j] + bv;
          size_t o = (size_t)row * D_ + col;
          float base = (kpick == 0) ? Xb[o] : Ob[o];
          Ob[o] = base + wt * y;
        }
      }
    }
  }
}

// ---------------- launcher ----------------

extern "C" void kernel_launch(void* const* d_in, const int* in_sizes, int n_in,
                              void* d_out, int out_size, void* d_ws, size_t ws_size,
                              hipStream_t stream) {
  (void)in_sizes; (void)n_in; (void)out_size;
  const float* x      = (const float*)d_in[0];
  const float* gate_w = (const float*)d_in[1];
  const float* gate_b = (const float*)d_in[2];
  const float* w1     = (const float*)d_in[3];
  const float* b1     = (const float*)d_in[4];
  const float* w2     = (const float*)d_in[5];
  const float* b2     = (const float*)d_in[6];
  float* out = (float*)d_out;
  float* gate_out = out + (size_t)B_ * T_ * D_;

  char* ws = (char*)d_ws;
  size_t off = 0;
  auto alloc = [&](size_t bytes) -> void* {
    void* p = ws + off;
    off += (bytes + 255) & ~(size_t)255;
    return p;
  };
  u16* x16     = (u16*)alloc((size_t)B_ * T_ * D_ * 2);
  u16* w1t     = (u16*)alloc((size_t)E_ * H_ * D_ * 2);
  u16* w2t     = (u16*)alloc((size_t)E_ * D_ * H_ * 2);
  float* part  = (float*)alloc((size_t)B_ * 64 * D_ * 4);
  int* eidx    = (int*)alloc(B_ * 2 * sizeof(int));
  float* ewt   = (float*)alloc(B_ * 2 * sizeof(float));
  int BCH = 32;
  while (BCH > 1 && off + (size_t)BCH * T_ * H_ * 2 > ws_size) BCH >>= 1;
  u16* h = (u16*)alloc((size_t)BCH * T_ * H_ * 2);

  k_convert_x<<<dim3((B_ * T_ * D_ / 8) / 256), 256, 0, stream>>>(x, x16, B_ * T_ * D_ / 8);
  k_transpose_bf16<<<dim3(H_ / 64, D_ / 64, E_), 256, 0, stream>>>(w1, w1t, D_, H_);
  k_transpose_bf16<<<dim3(D_ / 64, H_ / 64, E_), 256, 0, stream>>>(w2, w2t, H_, D_);
  k_pool_partial<<<dim3(64, B_), 256, 0, stream>>>(x, part);
  k_gate<<<B_, 256, 0, stream>>>(part, gate_w, gate_b, gate_out, eidx, ewt);

  for (int bofs = 0; bofs < B_; bofs += BCH) {
    for (int k = 0; k < 2; k++) {
      moe_gemm<H_, D_, 0><<<dim3((T_ / 128) * (H_ / 128), BCH), 256, 0, stream>>>(
          x16 + (size_t)bofs * T_ * D_, w1t, b1, h, nullptr, nullptr, eidx, ewt, k, bofs);
      moe_gemm<D_, H_, 1><<<dim3((T_ / 128) * (D_ / 128), BCH), 256, 0, stream>>>(
          h, w2t, b2, nullptr, out, x, eidx, ewt, k, bofs);
    }
  }
}

// Round 3
// 715.384 us; speedup vs baseline: 1.1153x; 1.1153x over previous
//
#include <hip/hip_runtime.h>
#include <stdint.h>

typedef unsigned short u16;
typedef __attribute__((ext_vector_type(8))) short short8;
typedef __attribute__((ext_vector_type(8))) u16 ushort8;
typedef __attribute__((ext_vector_type(4))) float f32x4;

#define B_ 32
#define T_ 1024
#define D_ 512
#define H_ 2048
#define E_ 8

__device__ __forceinline__ u16 f2bf(float f) {
  union { float f; uint32_t u; } v; v.f = f;
  uint32_t u = v.u;
  uint32_t r = (u + 0x7fffu + ((u >> 16) & 1u)) >> 16;
  return (u16)r;
}

__device__ __forceinline__ void gload16(const void* g, void* l) {
  __builtin_amdgcn_global_load_lds(
      (const __attribute__((address_space(1))) unsigned int*)g,
      (__attribute__((address_space(3))) unsigned int*)l, 16, 0, 0);
}

// ---------------- conversion / transpose ----------------

__global__ void k_convert_x(const float* __restrict__ in, u16* __restrict__ out, int n8) {
  int i = blockIdx.x * 256 + threadIdx.x;
  if (i >= n8) return;
  const float4* p = reinterpret_cast<const float4*>(in) + (size_t)i * 2;
  float4 a = p[0], b = p[1];
  ushort8 r;
  r[0] = f2bf(a.x); r[1] = f2bf(a.y); r[2] = f2bf(a.z); r[3] = f2bf(a.w);
  r[4] = f2bf(b.x); r[5] = f2bf(b.y); r[6] = f2bf(b.z); r[7] = f2bf(b.w);
  reinterpret_cast<ushort8*>(out)[i] = r;
}

// in: [E][R][C] f32  ->  out: [E][C][R] bf16
__global__ void k_transpose_bf16(const float* __restrict__ in, u16* __restrict__ out,
                                 int R, int C) {
  __shared__ float tile[64][65];
  int e = blockIdx.z;
  int c0 = blockIdx.x * 64, r0 = blockIdx.y * 64;
  const float* src = in + (size_t)e * R * C;
  u16* dst = out + (size_t)e * R * C;
  int t = threadIdx.x;
#pragma unroll
  for (int i = 0; i < 16; i++) {
    int idx = i * 256 + t;
    int r = idx >> 6, c = idx & 63;
    tile[r][c] = src[(size_t)(r0 + r) * C + (c0 + c)];
  }
  __syncthreads();
#pragma unroll
  for (int i = 0; i < 16; i++) {
    int idx = i * 256 + t;
    int c = idx >> 6, r = idx & 63;
    dst[(size_t)(c0 + c) * R + (r0 + r)] = f2bf(tile[r][c]);
  }
}

// ---------------- gating ----------------

__global__ void k_pool_partial(const float* __restrict__ x, float* __restrict__ partial) {
  int b = blockIdx.y, c = blockIdx.x, t = threadIdx.x;
  const float* xp = x + ((size_t)b * T_ + c * 16) * D_;
  float s0 = 0.f, s1 = 0.f;
#pragma unroll
  for (int r = 0; r < 16; r++) {
    s0 += xp[r * D_ + t];
    s1 += xp[r * D_ + t + 256];
  }
  partial[((size_t)b * 64 + c) * D_ + t] = s0;
  partial[((size_t)b * 64 + c) * D_ + t + 256] = s1;
}

__global__ void k_gate(const float* __restrict__ partial, const float* __restrict__ gate_w,
                       const float* __restrict__ gate_b, float* __restrict__ gate_out,
                       int* __restrict__ eidx, float* __restrict__ ewt) {
  int b = blockIdx.x, t = threadIdx.x;
  __shared__ float pooled[D_];
  __shared__ float logits[E_];
  for (int d = t; d < D_; d += 256) {
    float s = 0.f;
    for (int c = 0; c < 64; c++) s += partial[((size_t)b * 64 + c) * D_ + d];
    pooled[d] = s * (1.0f / 1024.0f);
  }
  __syncthreads();
  if (t < E_) {
    float s = gate_b[t];
    for (int d = 0; d < D_; d++) s += pooled[d] * gate_w[d * E_ + t];
    logits[t] = s;
    gate_out[b * E_ + t] = s;
  }
  __syncthreads();
  if (t == 0) {
    int i1 = 0; float v1 = logits[0];
    for (int e = 1; e < E_; e++) if (logits[e] > v1) { v1 = logits[e]; i1 = e; }
    int i2 = -1; float v2 = -3.4e38f;
    for (int e = 0; e < E_; e++) {
      if (e == i1) continue;
      if (logits[e] > v2) { v2 = logits[e]; i2 = e; }
    }
    float e1 = __expf(v2 - v1);
    float den = 1.0f / (1.0f + e1);
    eidx[b * 2 + 0] = i1; eidx[b * 2 + 1] = i2;
    ewt[b * 2 + 0] = den; ewt[b * 2 + 1] = e1 * den;
  }
}

// ---------------- 8-wave 256x256 ring-4 pipelined expert GEMM ----------------
// A: [chunk][1024][K] bf16 row-major. W: [E][N][K] bf16 (pre-transposed, [N][K]).
// 512 threads = 8 waves (2 Mx4 N), per-wave 128x64 output, BK=32.
// LDS: 4-slot ring x (A 16KB + B 16KB) = 128KB dynamic.
// Swizzle: 16B chunk index ch' = ch ^ ((row>>1)&3), applied on global source
// (stage) and on ds_read address (both-sides involution). Linear gload_lds dest.
// MODE 0: Hout = silu(A@W^T + b1[e]);  MODE 1: Out = base + wt*(A@W^T + b2[e])
template <int N, int K, int MODE>
__global__ __launch_bounds__(512, 2)
void moe_gemm8(const u16* __restrict__ A, const u16* __restrict__ W,
               const float* __restrict__ bias, u16* __restrict__ Hout,
               float* __restrict__ Out, const float* __restrict__ Xres,
               const int* __restrict__ eidx, const float* __restrict__ ewt,
               int kpick, int bofs) {
  extern __shared__ u16 lds[];  // [4][8192] A slots, then [4][8192] B slots
  constexpr int NT = K / 32;    // K-tiles (>= 16)
  constexpr int NTN = N / 256;
  const int ib = blockIdx.y;
  const int b = ib + bofs;
  const int tm = blockIdx.x / NTN, tn = blockIdx.x % NTN;
  const int e = eidx[b * 2 + kpick];
  const int tid = threadIdx.x;
  const int wave = tid >> 6, ln = tid & 63, hi = ln >> 4, l15 = ln & 15;
  const int wr = wave >> 2, wc = wave & 3;

  u16* As = lds;
  u16* Bs = lds + 32768;

  const u16* Ab = A + (size_t)ib * T_ * K + (size_t)(tm * 256) * K;
  const u16* Wb = W + (size_t)e * N * K + (size_t)(tn * 256) * K;

  // staging geometry: thread tid covers LDS 16B chunk (j*8192B + tid*16B)
  const int row0 = tid >> 2;        // j=0: rows 0..127
  const int row1 = 128 + row0;      // j=1: rows 128..255
  const int ch0 = (tid & 3) ^ ((row0 >> 1) & 3);  // inverse-swizzled source chunk
  const int ch1 = (tid & 3) ^ ((row1 >> 1) & 3);
  const int ldsw0 = wave * 512;          // u16, wave-uniform dest base, j=0
  const int ldsw1 = 4096 + wave * 512;   // j=1

  auto stageA = [&](int t) {
    const u16* g = Ab + t * 32;
    u16* l = As + (t & 3) * 8192;
    gload16(g + (size_t)row0 * K + ch0 * 8, l + ldsw0);
    gload16(g + (size_t)row1 * K + ch1 * 8, l + ldsw1);
  };
  auto stageB = [&](int t) {
    const u16* g = Wb + t * 32;
    u16* l = Bs + (t & 3) * 8192;
    gload16(g + (size_t)row0 * K + ch0 * 8, l + ldsw0);
    gload16(g + (size_t)row1 * K + ch1 * 8, l + ldsw1);
  };
  auto readA = [&](int bi, int m) -> short8 {
    const int r = wr * 128 + m * 16 + l15;
    const int cp = hi ^ ((r >> 1) & 3);
    return *reinterpret_cast<const short8*>(As + bi * 8192 + r * 32 + cp * 8);
  };
  auto readB = [&](int bi, int n) -> short8 {
    const int r = wc * 64 + n * 16 + l15;
    const int cp = hi ^ ((r >> 1) & 3);
    return *reinterpret_cast<const short8*>(Bs + bi * 8192 + r * 32 + cp * 8);
  };

  f32x4 acc[8][4] = {};

  // prologue: stage tiles 0,1,2 (12 loads/thread); tile0 guaranteed by vmcnt(8)
  stageA(0); stageB(0);
  stageA(1); stageB(1);
  stageA(2); stageB(2);
  asm volatile("s_waitcnt vmcnt(8)" ::: "memory");
  __builtin_amdgcn_s_barrier();
  __builtin_amdgcn_sched_barrier(0);

  for (int tb = 0; tb < NT; tb += 4) {
#pragma unroll
    for (int u = 0; u < 4; u++) {
      const int t = tb + u;
      const int bi = u;  // tb % 4 == 0
      short8 af[4], bfr[4];
      // ---- phase 0: read A[m0..3] + B[n0..3], prefetch A of tile t+3 ----
#pragma unroll
      for (int m = 0; m < 4; m++) af[m] = readA(bi, m);
#pragma unroll
      for (int n = 0; n < 4; n++) bfr[n] = readB(bi, n);
      if (t + 3 < NT) stageA(t + 3);
      __builtin_amdgcn_s_barrier();
      __builtin_amdgcn_sched_barrier(0);
      __builtin_amdgcn_s_setprio(1);
#pragma unroll
      for (int m = 0; m < 4; m++)
#pragma unroll
        for (int n = 0; n < 4; n++)
          acc[m][n] = __builtin_amdgcn_mfma_f32_16x16x32_bf16(af[m], bfr[n], acc[m][n], 0, 0, 0);
      __builtin_amdgcn_s_setprio(0);
      __builtin_amdgcn_s_barrier();
      // ---- phase 1: read A[m4..7] (B reused), prefetch B of tile t+3 ----
#pragma unroll
      for (int m = 0; m < 4; m++) af[m] = readA(bi, m + 4);
      if (t + 3 < NT) stageB(t + 3);
      __builtin_amdgcn_s_barrier();
      __builtin_amdgcn_sched_barrier(0);
      __builtin_amdgcn_s_setprio(1);
#pragma unroll
      for (int m = 0; m < 4; m++)
#pragma unroll
        for (int n = 0; n < 4; n++)
          acc[m + 4][n] = __builtin_amdgcn_mfma_f32_16x16x32_bf16(af[m], bfr[n], acc[m + 4][n], 0, 0, 0);
      __builtin_amdgcn_s_setprio(0);
      // ---- tile-end: counted vmcnt guarantees tile t+1 landed ----
      if (t < NT - 3)      { asm volatile("s_waitcnt vmcnt(8)" ::: "memory"); }
      else if (t == NT - 3){ asm volatile("s_waitcnt vmcnt(4)" ::: "memory"); }
      else if (t == NT - 2){ asm volatile("s_waitcnt vmcnt(0)" ::: "memory"); }
      __builtin_amdgcn_s_barrier();
      __builtin_amdgcn_sched_barrier(0);
    }
  }

  // ---------------- epilogue ----------------
  const float* be = bias + (size_t)e * N;
  if (MODE == 0) {
    u16* Hb = Hout + (size_t)ib * T_ * N;
#pragma unroll
    for (int m = 0; m < 8; m++) {
#pragma unroll
      for (int n = 0; n < 4; n++) {
        const int col = tn * 256 + wc * 64 + n * 16 + l15;
        const float bv = be[col];
#pragma unroll
        for (int j = 0; j < 4; j++) {
          const int row = tm * 256 + wr * 128 + m * 16 + hi * 4 + j;
          float z = acc[m][n][j] + bv;
          float hv = z / (1.0f + expf(-z));
          Hb[(size_t)row * N + col] = f2bf(hv);
        }
      }
    }
  } else {
    const float wt = ewt[b * 2 + kpick];
    float* Ob = Out + (size_t)b * T_ * D_;
    const float* Xb = Xres + (size_t)b * T_ * D_;
#pragma unroll
    for (int m = 0; m < 8; m++) {
#pragma unroll
      for (int n = 0; n < 4; n++) {
        const int col = tn * 256 + wc * 64 + n * 16 + l15;
        const float bv = be[col];
#pragma unroll
        for (int j = 0; j < 4; j++) {
          const int row = tm * 256 + wr * 128 + m * 16 + hi * 4 + j;
          float y = acc[m][n][j] + bv;
          size_t o = (size_t)row * D_ + col;
          float base = (kpick == 0) ? Xb[o] : Ob[o];
          Ob[o] = base + wt * y;
        }
      }
    }
  }
}

// ---------------- launcher ----------------

extern "C" void kernel_launch(void* const* d_in, const int* in_sizes, int n_in,
                              void* d_out, int out_size, void* d_ws, size_t ws_size,
                              hipStream_t stream) {
  (void)in_sizes; (void)n_in; (void)out_size;
  const float* x      = (const float*)d_in[0];
  const float* gate_w = (const float*)d_in[1];
  const float* gate_b = (const float*)d_in[2];
  const float* w1     = (const float*)d_in[3];
  const float* b1     = (const float*)d_in[4];
  const float* w2     = (const float*)d_in[5];
  const float* b2     = (const float*)d_in[6];
  float* out = (float*)d_out;
  float* gate_out = out + (size_t)B_ * T_ * D_;

  char* ws = (char*)d_ws;
  size_t off = 0;
  auto alloc = [&](size_t bytes) -> void* {
    void* p = ws + off;
    off += (bytes + 255) & ~(size_t)255;
    return p;
  };
  u16* x16     = (u16*)alloc((size_t)B_ * T_ * D_ * 2);
  u16* w1t     = (u16*)alloc((size_t)E_ * H_ * D_ * 2);
  u16* w2t     = (u16*)alloc((size_t)E_ * D_ * H_ * 2);
  float* part  = (float*)alloc((size_t)B_ * 64 * D_ * 4);
  int* eidx    = (int*)alloc(B_ * 2 * sizeof(int));
  float* ewt   = (float*)alloc(B_ * 2 * sizeof(float));
  int BCH = 32;
  while (BCH > 1 && off + (size_t)BCH * T_ * H_ * 2 > ws_size) BCH >>= 1;
  u16* h = (u16*)alloc((size_t)BCH * T_ * H_ * 2);

  // 128 KiB dynamic LDS opt-in (idempotent host-side call; capture-safe)
  constexpr int LDSB = 131072;
  (void)hipFuncSetAttribute((const void*)moe_gemm8<H_, D_, 0>,
                            hipFuncAttributeMaxDynamicSharedMemorySize, LDSB);
  (void)hipFuncSetAttribute((const void*)moe_gemm8<D_, H_, 1>,
                            hipFuncAttributeMaxDynamicSharedMemorySize, LDSB);

  k_convert_x<<<dim3((B_ * T_ * D_ / 8) / 256), 256, 0, stream>>>(x, x16, B_ * T_ * D_ / 8);
  k_transpose_bf16<<<dim3(H_ / 64, D_ / 64, E_), 256, 0, stream>>>(w1, w1t, D_, H_);
  k_transpose_bf16<<<dim3(D_ / 64, H_ / 64, E_), 256, 0, stream>>>(w2, w2t, H_, D_);
  k_pool_partial<<<dim3(64, B_), 256, 0, stream>>>(x, part);
  k_gate<<<B_, 256, 0, stream>>>(part, gate_w, gate_b, gate_out, eidx, ewt);

  for (int bofs = 0; bofs < B_; bofs += BCH) {
    for (int k = 0; k < 2; k++) {
      moe_gemm8<H_, D_, 0><<<dim3((T_ / 256) * (H_ / 256), BCH), 512, LDSB, stream>>>(
          x16 + (size_t)bofs * T_ * D_, w1t, b1, h, nullptr, nullptr, eidx, ewt, k, bofs);
      moe_gemm8<D_, H_, 1><<<dim3((T_ / 256) * (D_ / 256), BCH), 512, LDSB, stream>>>(
          h, w2t, b2, nullptr, out, x, eidx, ewt, k, bofs);
    }
  }
}

// Round 5
// 605.326 us; speedup vs baseline: 1.3181x; 1.1818x over previous
//
#include <hip/hip_runtime.h>
#include <stdint.h>

typedef unsigned short u16;
typedef __attribute__((ext_vector_type(8))) short short8;
typedef __attribute__((ext_vector_type(8))) u16 ushort8;
typedef __attribute__((ext_vector_type(4))) u16 u16x4;
typedef __attribute__((ext_vector_type(4))) float f32x4;

#define B_ 32
#define T_ 1024
#define D_ 512
#define H_ 2048
#define E_ 8

__device__ __forceinline__ u16 f2bf(float f) {
  union { float f; uint32_t u; } v; v.f = f;
  uint32_t u = v.u;
  uint32_t r = (u + 0x7fffu + ((u >> 16) & 1u)) >> 16;
  return (u16)r;
}

__device__ __forceinline__ void gload16(const void* g, void* l) {
  __builtin_amdgcn_global_load_lds(
      (const __attribute__((address_space(1))) unsigned int*)g,
      (__attribute__((address_space(3))) unsigned int*)l, 16, 0, 0);
}

// ---------------- conversion / transpose ----------------

__global__ void k_convert_x(const float* __restrict__ in, u16* __restrict__ out, int n8) {
  int i = blockIdx.x * 256 + threadIdx.x;
  if (i >= n8) return;
  const float4* p = reinterpret_cast<const float4*>(in) + (size_t)i * 2;
  float4 a = p[0], b = p[1];
  ushort8 r;
  r[0] = f2bf(a.x); r[1] = f2bf(a.y); r[2] = f2bf(a.z); r[3] = f2bf(a.w);
  r[4] = f2bf(b.x); r[5] = f2bf(b.y); r[6] = f2bf(b.z); r[7] = f2bf(b.w);
  reinterpret_cast<ushort8*>(out)[i] = r;
}

// in: [E][R][C] f32  ->  out: [E][C][R] bf16
__global__ void k_transpose_bf16(const float* __restrict__ in, u16* __restrict__ out,
                                 int R, int C) {
  __shared__ float tile[64][65];
  int e = blockIdx.z;
  int c0 = blockIdx.x * 64, r0 = blockIdx.y * 64;
  const float* src = in + (size_t)e * R * C;
  u16* dst = out + (size_t)e * R * C;
  int t = threadIdx.x;
#pragma unroll
  for (int i = 0; i < 16; i++) {
    int idx = i * 256 + t;
    int r = idx >> 6, c = idx & 63;
    tile[r][c] = src[(size_t)(r0 + r) * C + (c0 + c)];
  }
  __syncthreads();
#pragma unroll
  for (int i = 0; i < 16; i++) {
    int idx = i * 256 + t;
    int c = idx >> 6, r = idx & 63;
    dst[(size_t)(c0 + c) * R + (r0 + r)] = f2bf(tile[r][c]);
  }
}

// ---------------- gating ----------------

__global__ void k_pool_partial(const float* __restrict__ x, float* __restrict__ partial) {
  int b = blockIdx.y, c = blockIdx.x, t = threadIdx.x;
  const float* xp = x + ((size_t)b * T_ + c * 16) * D_;
  float s0 = 0.f, s1 = 0.f;
#pragma unroll
  for (int r = 0; r < 16; r++) {
    s0 += xp[r * D_ + t];
    s1 += xp[r * D_ + t + 256];
  }
  partial[((size_t)b * 64 + c) * D_ + t] = s0;
  partial[((size_t)b * 64 + c) * D_ + t + 256] = s1;
}

__global__ void k_gate(const float* __restrict__ partial, const float* __restrict__ gate_w,
                       const float* __restrict__ gate_b, float* __restrict__ gate_out,
                       int* __restrict__ eidx, float* __restrict__ ewt) {
  int b = blockIdx.x, t = threadIdx.x;
  __shared__ float pooled[D_];
  __shared__ float logits[E_];
  for (int d = t; d < D_; d += 256) {
    float s = 0.f;
    for (int c = 0; c < 64; c++) s += partial[((size_t)b * 64 + c) * D_ + d];
    pooled[d] = s * (1.0f / 1024.0f);
  }
  __syncthreads();
  if (t < E_) {
    float s = gate_b[t];
    for (int d = 0; d < D_; d++) s += pooled[d] * gate_w[d * E_ + t];
    logits[t] = s;
    gate_out[b * E_ + t] = s;
  }
  __syncthreads();
  if (t == 0) {
    int i1 = 0; float v1 = logits[0];
    for (int e = 1; e < E_; e++) if (logits[e] > v1) { v1 = logits[e]; i1 = e; }
    int i2 = -1; float v2 = -3.4e38f;
    for (int e = 0; e < E_; e++) {
      if (e == i1) continue;
      if (logits[e] > v2) { v2 = logits[e]; i2 = e; }
    }
    float e1 = __expf(v2 - v1);
    float den = 1.0f / (1.0f + e1);
    eidx[b * 2 + 0] = i1; eidx[b * 2 + 1] = i2;
    ewt[b * 2 + 0] = den; ewt[b * 2 + 1] = e1 * den;
  }
}

// ------- 8-wave 256x256 ring-4, register read-ahead, 1 barrier/K-tile -------
// A: [chunk][1024][K] bf16 row-major. W: [E][N][K] bf16 (pre-transposed).
// Swapped MFMA (bf, af) -> thread holds 4 consecutive output cols per frag.
// MODE 0: Hout = silu(A@W^T + b1[e]);  MODE 1: Out = base + wt*(A@W^T + b2[e])

#define TILE_BODY(BFC, BFN, T, DOSTAGE, DORD, VMODE) do {                      \
  const int sc_ = ((T) & 3) * 8192, sn_ = (((T) + 1) & 3) * 8192;              \
  _Pragma("unroll") for (int m_ = 0; m_ < 4; m_++) a4[m_] = rdA(sc_, m_ + 4);  \
  if (DORD) { _Pragma("unroll") for (int n_ = 0; n_ < 4; n_++) BFN[n_] = rdB(sn_, n_); } \
  if (DOSTAGE) { stageA((T) + 3); stageB((T) + 3); }                           \
  __builtin_amdgcn_sched_barrier(0);                                           \
  __builtin_amdgcn_s_setprio(1);                                               \
  _Pragma("unroll") for (int m_ = 0; m_ < 4; m_++)                             \
    _Pragma("unroll") for (int n_ = 0; n_ < 4; n_++)                           \
      acc[m_][n_] = __builtin_amdgcn_mfma_f32_16x16x32_bf16(BFC[n_], a0[m_], acc[m_][n_], 0, 0, 0); \
  __builtin_amdgcn_s_setprio(0);                                               \
  if (DORD) { _Pragma("unroll") for (int m_ = 0; m_ < 4; m_++) a0[m_] = rdA(sn_, m_); } \
  __builtin_amdgcn_sched_barrier(0);                                           \
  __builtin_amdgcn_s_setprio(1);                                               \
  _Pragma("unroll") for (int m_ = 0; m_ < 4; m_++)                             \
    _Pragma("unroll") for (int n_ = 0; n_ < 4; n_++)                           \
      acc[m_ + 4][n_] = __builtin_amdgcn_mfma_f32_16x16x32_bf16(BFC[n_], a4[m_], acc[m_ + 4][n_], 0, 0, 0); \
  __builtin_amdgcn_s_setprio(0);                                               \
  if ((VMODE) == 1) { asm volatile("s_waitcnt vmcnt(4)" ::: "memory"); }       \
  else if ((VMODE) == 0) { asm volatile("s_waitcnt vmcnt(0)" ::: "memory"); }  \
  __builtin_amdgcn_s_barrier();                                                \
  __builtin_amdgcn_sched_barrier(0);                                           \
} while (0)

template <int N, int K, int MODE>
__global__ __launch_bounds__(512, 2)
void moe_gemm8(const u16* __restrict__ A, const u16* __restrict__ W,
               const float* __restrict__ bias, u16* __restrict__ Hout,
               float* __restrict__ Out, const float* __restrict__ Xres,
               const int* __restrict__ eidx, const float* __restrict__ ewt,
               int kpick, int bofs) {
  extern __shared__ u16 lds[];  // A: 4 slots x 8192 u16; B: same at +32768
  constexpr int NT = K / 32;    // K-tiles (16 or 64)
  constexpr int NTN = N / 256;
  const int ib = blockIdx.y;
  const int b = ib + bofs;
  const int tm = blockIdx.x / NTN, tn = blockIdx.x % NTN;
  const int e = eidx[b * 2 + kpick];
  const int tid = threadIdx.x;
  const int wave = tid >> 6, ln = tid & 63, hi = ln >> 4, l15 = ln & 15;
  const int wr = wave >> 2, wc = wave & 3;

  u16* As = lds;
  u16* Bs = lds + 32768;

  const u16* Ab = A + (size_t)ib * T_ * K + (size_t)(tm * 256) * K;
  const u16* Wb = W + (size_t)e * N * K + (size_t)(tn * 256) * K;

  const int row0 = tid >> 2;
  const int row1 = 128 + row0;
  const int ch0 = (tid & 3) ^ ((row0 >> 1) & 3);
  const int ch1 = (tid & 3) ^ ((row1 >> 1) & 3);
  const int ldsw0 = wave * 512;
  const int ldsw1 = 4096 + wave * 512;

  auto stageA = [&](int t) {
    const u16* g = Ab + t * 32;
    u16* l = As + (t & 3) * 8192;
    gload16(g + (size_t)row0 * K + ch0 * 8, l + ldsw0);
    gload16(g + (size_t)row1 * K + ch1 * 8, l + ldsw1);
  };
  auto stageB = [&](int t) {
    const u16* g = Wb + t * 32;
    u16* l = Bs + (t & 3) * 8192;
    gload16(g + (size_t)row0 * K + ch0 * 8, l + ldsw0);
    gload16(g + (size_t)row1 * K + ch1 * 8, l + ldsw1);
  };
  auto rdA = [&](int so, int m) -> short8 {
    const int r = wr * 128 + m * 16 + l15;
    const int cp = hi ^ ((r >> 1) & 3);
    return *reinterpret_cast<const short8*>(As + so + r * 32 + cp * 8);
  };
  auto rdB = [&](int so, int n) -> short8 {
    const int r = wc * 64 + n * 16 + l15;
    const int cp = hi ^ ((r >> 1) & 3);
    return *reinterpret_cast<const short8*>(Bs + so + r * 32 + cp * 8);
  };

  f32x4 acc[8][4] = {};
  short8 a0[4], a4[4], bfA[4], bfB[4];

  // prologue: stage tiles 0..2; wait tiles 0,1; pre-read frags of tile 0
  stageA(0); stageB(0);
  stageA(1); stageB(1);
  stageA(2); stageB(2);
  asm volatile("s_waitcnt vmcnt(4)" ::: "memory");
  __builtin_amdgcn_s_barrier();
  __builtin_amdgcn_sched_barrier(0);
#pragma unroll
  for (int m = 0; m < 4; m++) a0[m] = rdA(0, m);
#pragma unroll
  for (int n = 0; n < 4; n++) bfA[n] = rdB(0, n);

  for (int t = 0; t < NT - 4; t += 2) {
    TILE_BODY(bfA, bfB, t,     true,  true,  1);
    TILE_BODY(bfB, bfA, t + 1, true,  true,  1);
  }
  TILE_BODY(bfA, bfB, NT - 4, true,  true,  1);
  TILE_BODY(bfB, bfA, NT - 3, false, true,  0);
  TILE_BODY(bfA, bfB, NT - 2, false, true,  -1);
  TILE_BODY(bfB, bfA, NT - 1, false, false, -1);

  // ---------------- epilogue (swapped layout: row=m*16+l15, col=n*16+hi*4+j) --
  const float* be = bias + (size_t)e * N + tn * 256 + wc * 64 + hi * 4;
  f32x4 bv[4];
#pragma unroll
  for (int n = 0; n < 4; n++) bv[n] = *reinterpret_cast<const f32x4*>(be + n * 16);

  if (MODE == 0) {
    u16* Hb = Hout + (size_t)ib * T_ * N +
              (size_t)(tm * 256 + wr * 128 + l15) * N + tn * 256 + wc * 64 + hi * 4;
#pragma unroll
    for (int m = 0; m < 8; m++) {
      u16* Hr = Hb + (size_t)m * 16 * N;
#pragma unroll
      for (int n = 0; n < 4; n++) {
        u16x4 o;
#pragma unroll
        for (int j = 0; j < 4; j++) {
          float z = acc[m][n][j] + bv[n][j];
          float hv = z * __builtin_amdgcn_rcpf(1.0f + __expf(-z));
          o[j] = f2bf(hv);
        }
        *reinterpret_cast<u16x4*>(Hr + n * 16) = o;
      }
    }
  } else {
    const float wt = ewt[b * 2 + kpick];
    const size_t rowoff = (size_t)(tm * 256 + wr * 128 + l15) * D_ + tn * 256 + wc * 64 + hi * 4;
    float* Ob = Out + (size_t)b * T_ * D_ + rowoff;
    const float* Xb = Xres + (size_t)b * T_ * D_ + rowoff;
#pragma unroll
    for (int m = 0; m < 8; m++) {
#pragma unroll
      for (int n = 0; n < 4; n++) {
        const size_t o = (size_t)m * 16 * D_ + n * 16;
        f32x4 y = acc[m][n] + bv[n];
        f32x4 base = (kpick == 0) ? *reinterpret_cast<const f32x4*>(Xb + o)
                                  : *reinterpret_cast<const f32x4*>(Ob + o);
        *reinterpret_cast<f32x4*>(Ob + o) = base + wt * y;
      }
    }
  }
}

// ---------------- launcher ----------------

extern "C" void kernel_launch(void* const* d_in, const int* in_sizes, int n_in,
                              void* d_out, int out_size, void* d_ws, size_t ws_size,
                              hipStream_t stream) {
  (void)in_sizes; (void)n_in; (void)out_size;
  const float* x      = (const float*)d_in[0];
  const float* gate_w = (const float*)d_in[1];
  const float* gate_b = (const float*)d_in[2];
  const float* w1     = (const float*)d_in[3];
  const float* b1     = (const float*)d_in[4];
  const float* w2     = (const float*)d_in[5];
  const float* b2     = (const float*)d_in[6];
  float* out = (float*)d_out;
  float* gate_out = out + (size_t)B_ * T_ * D_;

  char* ws = (char*)d_ws;
  size_t off = 0;
  auto alloc = [&](size_t bytes) -> void* {
    void* p = ws + off;
    off += (bytes + 255) & ~(size_t)255;
    return p;
  };
  u16* x16     = (u16*)alloc((size_t)B_ * T_ * D_ * 2);
  u16* w1t     = (u16*)alloc((size_t)E_ * H_ * D_ * 2);
  u16* w2t     = (u16*)alloc((size_t)E_ * D_ * H_ * 2);
  float* part  = (float*)alloc((size_t)B_ * 64 * D_ * 4);
  int* eidx    = (int*)alloc(B_ * 2 * sizeof(int));
  float* ewt   = (float*)alloc(B_ * 2 * sizeof(float));
  int BCH = 32;
  while (BCH > 1 && off + (size_t)BCH * T_ * H_ * 2 > ws_size) BCH >>= 1;
  u16* h = (u16*)alloc((size_t)BCH * T_ * H_ * 2);

  constexpr int LDSB = 131072;
  (void)hipFuncSetAttribute((const void*)moe_gemm8<H_, D_, 0>,
                            hipFuncAttributeMaxDynamicSharedMemorySize, LDSB);
  (void)hipFuncSetAttribute((const void*)moe_gemm8<D_, H_, 1>,
                            hipFuncAttributeMaxDynamicSharedMemorySize, LDSB);

  k_convert_x<<<dim3((B_ * T_ * D_ / 8) / 256), 256, 0, stream>>>(x, x16, B_ * T_ * D_ / 8);
  k_transpose_bf16<<<dim3(H_ / 64, D_ / 64, E_), 256, 0, stream>>>(w1, w1t, D_, H_);
  k_transpose_bf16<<<dim3(D_ / 64, H_ / 64, E_), 256, 0, stream>>>(w2, w2t, H_, D_);
  k_pool_partial<<<dim3(64, B_), 256, 0, stream>>>(x, part);
  k_gate<<<B_, 256, 0, stream>>>(part, gate_w, gate_b, gate_out, eidx, ewt);

  for (int bofs = 0; bofs < B_; bofs += BCH) {
    for (int k = 0; k < 2; k++) {
      moe_gemm8<H_, D_, 0><<<dim3((T_ / 256) * (H_ / 256), BCH), 512, LDSB, stream>>>(
          x16 + (size_t)bofs * T_ * D_, w1t, b1, h, nullptr, nullptr, eidx, ewt, k, bofs);
      moe_gemm8<D_, H_, 1><<<dim3((T_ / 256) * (D_ / 256), BCH), 512, LDSB, stream>>>(
          h, w2t, b2, nullptr, out, x, eidx, ewt, k, bofs);
    }
  }
}

// Round 6
// 585.095 us; speedup vs baseline: 1.3636x; 1.0346x over previous
//
#include <hip/hip_runtime.h>
#include <stdint.h>

typedef unsigned short u16;
typedef __attribute__((ext_vector_type(8))) short short8;
typedef __attribute__((ext_vector_type(8))) u16 ushort8;
typedef __attribute__((ext_vector_type(4))) u16 u16x4;
typedef __attribute__((ext_vector_type(4))) float f32x4;

#define B_ 32
#define T_ 1024
#define D_ 512
#define H_ 2048
#define E_ 8

__device__ __forceinline__ u16 f2bf(float f) {
  union { float f; uint32_t u; } v; v.f = f;
  uint32_t u = v.u;
  uint32_t r = (u + 0x7fffu + ((u >> 16) & 1u)) >> 16;
  return (u16)r;
}

__device__ __forceinline__ void gload16(const void* g, void* l) {
  __builtin_amdgcn_global_load_lds(
      (const __attribute__((address_space(1))) unsigned int*)g,
      (__attribute__((address_space(3))) unsigned int*)l, 16, 0, 0);
}

// ---------------- fused x conversion + pool partial ----------------
// block (c,b): rows c*16..c*16+16 of batch b; convert to bf16 + column sums
__global__ void k_convx_pool(const float* __restrict__ x, u16* __restrict__ x16,
                             float* __restrict__ partial) {
  int b = blockIdx.y, c = blockIdx.x, t = threadIdx.x;
  const float* xp = x + ((size_t)b * T_ + c * 16) * D_;
  u16* op = x16 + ((size_t)b * T_ + c * 16) * D_;
  float s0 = 0.f, s1 = 0.f;
#pragma unroll
  for (int r = 0; r < 16; r++) {
    float v0 = xp[r * D_ + t];
    float v1 = xp[r * D_ + t + 256];
    s0 += v0; s1 += v1;
    op[r * D_ + t] = f2bf(v0);
    op[r * D_ + t + 256] = f2bf(v1);
  }
  partial[((size_t)b * 64 + c) * D_ + t] = s0;
  partial[((size_t)b * 64 + c) * D_ + t + 256] = s1;
}

// in: [E][R][C] f32  ->  out: [E][C][R] bf16
__global__ void k_transpose_bf16(const float* __restrict__ in, u16* __restrict__ out,
                                 int R, int C) {
  __shared__ float tile[64][65];
  int e = blockIdx.z;
  int c0 = blockIdx.x * 64, r0 = blockIdx.y * 64;
  const float* src = in + (size_t)e * R * C;
  u16* dst = out + (size_t)e * R * C;
  int t = threadIdx.x;
#pragma unroll
  for (int i = 0; i < 16; i++) {
    int idx = i * 256 + t;
    int r = idx >> 6, c = idx & 63;
    tile[r][c] = src[(size_t)(r0 + r) * C + (c0 + c)];
  }
  __syncthreads();
#pragma unroll
  for (int i = 0; i < 16; i++) {
    int idx = i * 256 + t;
    int c = idx >> 6, r = idx & 63;
    dst[(size_t)(c0 + c) * R + (r0 + r)] = f2bf(tile[r][c]);
  }
}

// ---------------- gating ----------------

__global__ void k_gate(const float* __restrict__ partial, const float* __restrict__ gate_w,
                       const float* __restrict__ gate_b, float* __restrict__ gate_out,
                       int* __restrict__ eidx, float* __restrict__ ewt) {
  int b = blockIdx.x, t = threadIdx.x;
  __shared__ float pooled[D_];
  __shared__ float logits[E_];
  for (int d = t; d < D_; d += 256) {
    float s = 0.f;
    for (int c = 0; c < 64; c++) s += partial[((size_t)b * 64 + c) * D_ + d];
    pooled[d] = s * (1.0f / 1024.0f);
  }
  __syncthreads();
  if (t < E_) {
    float s = gate_b[t];
    for (int d = 0; d < D_; d++) s += pooled[d] * gate_w[d * E_ + t];
    logits[t] = s;
    gate_out[b * E_ + t] = s;
  }
  __syncthreads();
  if (t == 0) {
    int i1 = 0; float v1 = logits[0];
    for (int e = 1; e < E_; e++) if (logits[e] > v1) { v1 = logits[e]; i1 = e; }
    int i2 = -1; float v2 = -3.4e38f;
    for (int e = 0; e < E_; e++) {
      if (e == i1) continue;
      if (logits[e] > v2) { v2 = logits[e]; i2 = e; }
    }
    float e1 = __expf(v2 - v1);
    float den = 1.0f / (1.0f + e1);
    eidx[b * 2 + 0] = i1; eidx[b * 2 + 1] = i2;
    ewt[b * 2 + 0] = den; ewt[b * 2 + 1] = e1 * den;
  }
}

// ---------- 128x256-tile ring-3 GEMM, 8 waves, 2 blocks/CU ----------
// MODE 0 (G1): per (b, kz): h[kz][ib] = ewt*silu(x16[b] @ w1t[e]^T + b1[e])
//              K=512, N=2048, NTT=16 K-tiles
// MODE 1 (G2): out[b] = x[b] + sum_seg h[seg][ib] @ w2t[e_seg]^T + combined bias
//              K=2048 x 2 segments, N=512, NTT=128 K-tiles (pipeline flows across)
// LDS ring: 3 slots x (A 128x32 + B 256x32) bf16 = 3 x 24KB = 72KB
// Swizzle: 16B chunk ch' = ch ^ ((row>>1)&3) on stage-source and frag-read.
template <int MODE>
__global__ __launch_bounds__(512, 4)
void moe_gemm(const u16* __restrict__ Ax, const u16* __restrict__ Wt,
              const float* __restrict__ bias, u16* __restrict__ Hout,
              float* __restrict__ Out, const float* __restrict__ Xres,
              const int* __restrict__ eidx, const float* __restrict__ ewt,
              int bofs, int BCH) {
  constexpr int KS  = (MODE == 0) ? 512 : 2048;   // K per segment = row stride
  constexpr int NN  = (MODE == 0) ? 2048 : 512;
  constexpr int NTK = KS / 32;
  constexpr int NTT = (MODE == 0) ? NTK : 2 * NTK;
  constexpr int NTN = NN / 256;                   // 8 or 2
  constexpr int TPB = (T_ / 128) * NTN;           // 64 or 16

  extern __shared__ u16 lds[];  // 3 slots x 12288 u16 (A 4096 + B 8192)

  // bijective XCD swizzle: each XCD owns a contiguous nf range (batch-major)
  const int nwg = gridDim.x * gridDim.y * gridDim.z;
  const int flat = blockIdx.x + gridDim.x * (blockIdx.y + gridDim.y * blockIdx.z);
  const int per = nwg >> 3;
  const int nf = (flat & 7) * per + (flat >> 3);

  int ib, kz, tm, tn;
  if (MODE == 0) {
    ib = nf / (TPB * 2);
    int rem = nf % (TPB * 2);
    kz = rem / TPB;
    int xx = rem % TPB;
    tm = xx >> 3; tn = xx & 7;
  } else {
    ib = nf / TPB;
    int xx = nf % TPB;
    tm = xx >> 1; tn = xx & 1;
    kz = 0;
  }
  const int b = ib + bofs;

  const int tid = threadIdx.x;
  const int wave = tid >> 6, lane = tid & 63, hi = lane >> 4, l15 = lane & 15;
  const int wr = wave >> 2, wc = wave & 3;

  // segment bases
  const u16* Aseg[2]; const u16* Bseg[2];
  int e0 = 0, e1 = 0;
  if (MODE == 0) {
    e0 = eidx[b * 2 + kz];
    const u16* a = Ax + ((size_t)b * T_ + tm * 128) * 512;
    Aseg[0] = a; Aseg[1] = a;
    const u16* w = Wt + (size_t)e0 * H_ * 512 + (size_t)(tn * 256) * 512;
    Bseg[0] = w; Bseg[1] = w;
  } else {
    e0 = eidx[b * 2 + 0]; e1 = eidx[b * 2 + 1];
    Aseg[0] = Ax + ((size_t)(0 * BCH + ib) * T_ + tm * 128) * H_;
    Aseg[1] = Ax + ((size_t)(1 * BCH + ib) * T_ + tm * 128) * H_;
    Bseg[0] = Wt + (size_t)e0 * D_ * H_ + (size_t)(tn * 256) * H_;
    Bseg[1] = Wt + (size_t)e1 * D_ * H_ + (size_t)(tn * 256) * H_;
  }

  // staging geometry (1 A-load + 2 B-loads per thread per K-tile)
  const int rA = tid >> 2;
  const int cA = (tid & 3) ^ ((rA >> 1) & 3);
  const int rB1 = 128 + rA;
  const int cB0 = cA;                              // same row index -> same xor
  const int cB1 = (tid & 3) ^ ((rB1 >> 1) & 3);
  const int wbase = wave * 512;                    // wave-uniform u16 dest base

  auto stage = [&](int t, int so) {
    const int seg = t / NTK;
    const int kb = (t % NTK) * 32;
    gload16(Aseg[seg] + (size_t)rA * KS + kb + cA * 8, lds + so + wbase);
    gload16(Bseg[seg] + (size_t)rA * KS + kb + cB0 * 8, lds + so + 4096 + wbase);
    gload16(Bseg[seg] + (size_t)rB1 * KS + kb + cB1 * 8, lds + so + 8192 + wbase);
  };
  auto rdA = [&](int so, int m) -> short8 {
    const int r = wr * 64 + m * 16 + l15;
    const int cp = hi ^ ((r >> 1) & 3);
    return *reinterpret_cast<const short8*>(lds + so + r * 32 + cp * 8);
  };
  auto rdB = [&](int so, int n) -> short8 {
    const int r = wc * 64 + n * 16 + l15;
    const int cp = hi ^ ((r >> 1) & 3);
    return *reinterpret_cast<const short8*>(lds + so + 4096 + r * 32 + cp * 8);
  };

  f32x4 acc[4][4] = {};

  // prologue: stage tiles 0,1; wait tile 0 (allow tile 1's 3 loads in flight)
  stage(0, 0);
  stage(1, 12288);
  asm volatile("s_waitcnt vmcnt(3)" ::: "memory");
  __builtin_amdgcn_s_barrier();
  __builtin_amdgcn_sched_barrier(0);

  int so0 = 0, so1 = 12288, so2 = 24576;
  for (int tt = 0; tt < NTT; ++tt) {
    if (tt + 2 < NTT) stage(tt + 2, so2);
    short8 af[4], bg[4];
#pragma unroll
    for (int m = 0; m < 4; m++) af[m] = rdA(so0, m);
#pragma unroll
    for (int n = 0; n < 4; n++) bg[n] = rdB(so0, n);
    __builtin_amdgcn_sched_barrier(0);
    __builtin_amdgcn_s_setprio(1);
#pragma unroll
    for (int m = 0; m < 4; m++)
#pragma unroll
      for (int n = 0; n < 4; n++)
        acc[m][n] = __builtin_amdgcn_mfma_f32_16x16x32_bf16(bg[n], af[m], acc[m][n], 0, 0, 0);
    __builtin_amdgcn_s_setprio(0);
    if (tt < NTT - 2)       { asm volatile("s_waitcnt vmcnt(3)" ::: "memory"); }
    else if (tt == NTT - 2) { asm volatile("s_waitcnt vmcnt(0)" ::: "memory"); }
    __builtin_amdgcn_s_barrier();
    __builtin_amdgcn_sched_barrier(0);
    const int ts = so0; so0 = so1; so1 = so2; so2 = ts;
  }

  // epilogue (swapped layout: row = m*16 + l15, col = n*16 + hi*4 + j)
  const int row0 = tm * 128 + wr * 64 + l15;
  const int col0 = tn * 256 + wc * 64 + hi * 4;

  if (MODE == 0) {
    const float wt = ewt[b * 2 + kz];
    const float* be = bias + (size_t)e0 * 2048 + col0;
    u16* Hb = Hout + (((size_t)kz * BCH + ib) * T_ + row0) * 2048 + col0;
#pragma unroll
    for (int m = 0; m < 4; m++) {
      u16* Hr = Hb + (size_t)(m * 16) * 2048;
#pragma unroll
      for (int n = 0; n < 4; n++) {
        u16x4 o;
#pragma unroll
        for (int j = 0; j < 4; j++) {
          float z = acc[m][n][j] + be[n * 16 + j];
          float hv = wt * z * __builtin_amdgcn_rcpf(1.0f + __expf(-z));
          o[j] = f2bf(hv);
        }
        *reinterpret_cast<u16x4*>(Hr + n * 16) = o;
      }
    }
  } else {
    const float w0s = ewt[b * 2 + 0], w1s = ewt[b * 2 + 1];
    const float* ba = bias + (size_t)e0 * D_ + col0;
    const float* bb = bias + (size_t)e1 * D_ + col0;
    f32x4 bv[4];
#pragma unroll
    for (int n = 0; n < 4; n++)
#pragma unroll
      for (int j = 0; j < 4; j++)
        bv[n][j] = w0s * ba[n * 16 + j] + w1s * bb[n * 16 + j];
    float* Ob = Out + ((size_t)b * T_ + row0) * D_ + col0;
    const float* Xb = Xres + ((size_t)b * T_ + row0) * D_ + col0;
#pragma unroll
    for (int m = 0; m < 4; m++) {
#pragma unroll
      for (int n = 0; n < 4; n++) {
        const size_t o = (size_t)(m * 16) * D_ + n * 16;
        f32x4 base = *reinterpret_cast<const f32x4*>(Xb + o);
        *reinterpret_cast<f32x4*>(Ob + o) = base + acc[m][n] + bv[n];
      }
    }
  }
}

// ---------------- launcher ----------------

extern "C" void kernel_launch(void* const* d_in, const int* in_sizes, int n_in,
                              void* d_out, int out_size, void* d_ws, size_t ws_size,
                              hipStream_t stream) {
  (void)in_sizes; (void)n_in; (void)out_size;
  const float* x      = (const float*)d_in[0];
  const float* gate_w = (const float*)d_in[1];
  const float* gate_b = (const float*)d_in[2];
  const float* w1     = (const float*)d_in[3];
  const float* b1     = (const float*)d_in[4];
  const float* w2     = (const float*)d_in[5];
  const float* b2     = (const float*)d_in[6];
  float* out = (float*)d_out;
  float* gate_out = out + (size_t)B_ * T_ * D_;

  char* ws = (char*)d_ws;
  size_t off = 0;
  auto alloc = [&](size_t bytes) -> void* {
    void* p = ws + off;
    off += (bytes + 255) & ~(size_t)255;
    return p;
  };
  u16* x16     = (u16*)alloc((size_t)B_ * T_ * D_ * 2);
  u16* w1t     = (u16*)alloc((size_t)E_ * H_ * D_ * 2);
  u16* w2t     = (u16*)alloc((size_t)E_ * D_ * H_ * 2);
  float* part  = (float*)alloc((size_t)B_ * 64 * D_ * 4);
  int* eidx    = (int*)alloc(B_ * 2 * sizeof(int));
  float* ewt   = (float*)alloc(B_ * 2 * sizeof(float));
  int BCH = 32;
  while (BCH > 1 && off + (size_t)2 * BCH * T_ * H_ * 2 > ws_size) BCH >>= 1;
  u16* h = (u16*)alloc((size_t)2 * BCH * T_ * H_ * 2);  // h[2][BCH][T][H]

  constexpr int LDSB = 73728;  // 72 KiB -> 2 blocks/CU
  (void)hipFuncSetAttribute((const void*)moe_gemm<0>,
                            hipFuncAttributeMaxDynamicSharedMemorySize, LDSB);
  (void)hipFuncSetAttribute((const void*)moe_gemm<1>,
                            hipFuncAttributeMaxDynamicSharedMemorySize, LDSB);

  k_convx_pool<<<dim3(64, B_), 256, 0, stream>>>(x, x16, part);
  k_transpose_bf16<<<dim3(H_ / 64, D_ / 64, E_), 256, 0, stream>>>(w1, w1t, D_, H_);
  k_transpose_bf16<<<dim3(D_ / 64, H_ / 64, E_), 256, 0, stream>>>(w2, w2t, H_, D_);
  k_gate<<<B_, 256, 0, stream>>>(part, gate_w, gate_b, gate_out, eidx, ewt);

  for (int bofs = 0; bofs < B_; bofs += BCH) {
    // G1: both experts in one dispatch (z = expert slot), h pre-scaled by softmax wt
    moe_gemm<0><<<dim3(64, BCH, 2), 512, LDSB, stream>>>(
        x16, w1t, b1, h, nullptr, nullptr, eidx, ewt, bofs, BCH);
    // G2: single dispatch, K flows across both expert segments
    moe_gemm<1><<<dim3(16, BCH, 1), 512, LDSB, stream>>>(
        h, w2t, b2, nullptr, out, x, eidx, ewt, bofs, BCH);
  }
}